// Round 4
// baseline (503.723 us; speedup 1.0000x reference)
//
#include <hip/hip_runtime.h>
#include <hip/hip_bf16.h>
#include <stdint.h>

// Problem constants (B=4, T=1024, D=1024, E=8, HD=4096)
#define NE 8
#define DIM 1024
#define HDIM 4096
#define NTOK 4096
#define KSPLIT 4
#define MAXT 24     // max occupied 256-row m-tiles: 16 full + 8 partial
#define NT 16       // K-tiles of 64 per block (K=1024 for both gemms)

typedef unsigned short ushort_t;
typedef __attribute__((ext_vector_type(4))) float f32x4;
typedef __attribute__((ext_vector_type(8))) short bf16x8;
typedef __attribute__((ext_vector_type(8))) ushort_t u16x8;

#define WAITV(n) asm volatile("s_waitcnt vmcnt(" #n ")" ::: "memory")
#define WAITL0() asm volatile("s_waitcnt lgkmcnt(0)" ::: "memory")
#define WAITL8() asm volatile("s_waitcnt lgkmcnt(8)" ::: "memory")
#define SCHEDB() __builtin_amdgcn_sched_barrier(0)
#define BARRIER() __builtin_amdgcn_s_barrier()

// RNE float -> bf16 bits
__device__ __forceinline__ ushort_t f2b(float f) {
  union { float f; unsigned u; } c; c.f = f;
  unsigned u = c.u;
  return (ushort_t)((u + 0x7fffu + ((u >> 16) & 1u)) >> 16);
}

// async global->LDS, 16 bytes per lane; LDS dest = wave-uniform base + lane*16
__device__ __forceinline__ void gl2lds16(const void* g, void* l) {
  __builtin_amdgcn_global_load_lds(
      (__attribute__((address_space(1))) void*)g,
      (__attribute__((address_space(3))) void*)l, 16, 0, 0);
}

// MFMA quadrant: 4 M-frags x 2 N-frags x 2 k-slices = 16 MFMA (T5 setprio wrap)
#define PH_MFMA(mh, nh)                                                     \
  { __builtin_amdgcn_s_setprio(1);                                          \
    _Pragma("unroll")                                                       \
    for (int i2 = 0; i2 < 4; ++i2) {                                        \
      _Pragma("unroll")                                                     \
      for (int j2 = 0; j2 < 2; ++j2) {                                      \
        _Pragma("unroll")                                                   \
        for (int kk = 0; kk < 2; ++kk)                                      \
          acc[(mh)*4 + i2][(nh)*2 + j2] =                                   \
            __builtin_amdgcn_mfma_f32_16x16x32_bf16(                        \
              af[i2][kk], bf[(nh)*2 + j2][kk],                              \
              acc[(mh)*4 + i2][(nh)*2 + j2], 0, 0, 0);                      \
      }                                                                     \
    }                                                                       \
    __builtin_amdgcn_s_setprio(0); }

// frag loads; swizzled chunk index ck[] matches the staging-side involution
#define LOAD_AF(mh)                                                         \
  { _Pragma("unroll")                                                       \
    for (int i2 = 0; i2 < 4; ++i2) {                                        \
      _Pragma("unroll")                                                     \
      for (int kk = 0; kk < 2; ++kk)                                        \
        af[i2][kk] = *(const bf16x8*)&pA[aBase + ((mh)*64 + i2*16)*64 + ck[kk]]; \
    } }
#define LOAD_BF(nh)                                                         \
  { _Pragma("unroll")                                                       \
    for (int j2 = 0; j2 < 2; ++j2) {                                        \
      _Pragma("unroll")                                                     \
      for (int kk = 0; kk < 2; ++kk)                                        \
        bf[(nh)*2 + j2][kk] = *(const bf16x8*)&pB[bBase + (((nh)*2 + j2)*16)*64 + ck[kk]]; \
    } }

// ---------------- router: logits fp32 + argmax + count (fused) --------------
__global__ __launch_bounds__(256) void router_kernel(
    const float* __restrict__ x, const float* __restrict__ rw,
    int* __restrict__ eid, int* __restrict__ rank, int* __restrict__ cnt) {
  __shared__ float w[NE * 1028];
  for (int i = threadIdx.x; i < NE * DIM; i += 256) {
    int e = i >> 10, d = i & 1023;
    w[e * 1028 + d] = rw[i];
  }
  __syncthreads();
  int grp = threadIdx.x >> 3;
  int e = threadIdx.x & 7;
  int t = blockIdx.x * 32 + grp;
  const float4* xr = (const float4*)(x + (size_t)t * DIM);
  const float4* wr = (const float4*)(w + e * 1028);
  float acc = 0.f;
#pragma unroll 4
  for (int i = 0; i < DIM / 4; ++i) {
    float4 xv = xr[i], wv = wr[i];
    acc += xv.x * wv.x + xv.y * wv.y + xv.z * wv.z + xv.w * wv.w;
  }
  float v = acc; int ie = e;
#pragma unroll
  for (int m = 4; m; m >>= 1) {
    float ov = __shfl_xor(v, m, 8);
    int oi = __shfl_xor(ie, m, 8);
    if (ov > v || (ov == v && oi < ie)) { v = ov; ie = oi; }
  }
  if (e == 0) {
    eid[t] = ie;
    rank[t] = atomicAdd(&cnt[ie], 1);
  }
}

// prefix-sum + dense 256-row m-tile table
__global__ void scan_kernel(const int* __restrict__ cnt, int* __restrict__ offs,
                            int* __restrict__ tile_e, int* __restrict__ tile_m,
                            int* __restrict__ ntiles) {
  if (threadIdx.x == 0) {
    int s = 0, nt = 0;
    for (int e = 0; e < NE; ++e) {
      offs[e] = s;
      int c = cnt[e];
      for (int m = 0; m < c; m += 256) { tile_e[nt] = e; tile_m[nt] = m; ++nt; }
      s += c;
    }
    offs[NE] = s;
    *ntiles = nt;
  }
}

// one block per token: write sorted[] and gather x row -> bf16 grouped matrix
__global__ __launch_bounds__(256) void gather_kernel(
    const float* __restrict__ x, const int* __restrict__ eid,
    const int* __restrict__ rank, const int* __restrict__ offs,
    int* __restrict__ sorted, ushort_t* __restrict__ Xg) {
  int t = blockIdx.x;
  int e = eid[t];
  int pos = offs[e] + rank[t];
  if (threadIdx.x == 0) sorted[pos] = t;
  int i = threadIdx.x;
  float4 v = ((const float4*)(x + (size_t)t * DIM))[i];
  ushort4 o = make_ushort4(f2b(v.x), f2b(v.y), f2b(v.z), f2b(v.w));
  *(ushort4*)(Xg + (size_t)pos * DIM + i * 4) = o;
}

// ---------------- weight conversion ----------------------------------------
// fc[e][d][h] fp32 -> fct[e][h][d] bf16
__global__ __launch_bounds__(256) void transpose_fc_kernel(
    const float* __restrict__ fc, ushort_t* __restrict__ fct) {
  __shared__ float tile[64][68];
  int e = blockIdx.z;
  int h0 = blockIdx.x * 64, d0 = blockIdx.y * 64;
  int tid = threadIdx.x;
  int rr = tid >> 4;
  int cc = (tid & 15) * 4;
  const float* src = fc + ((size_t)e * DIM + d0 + rr) * HDIM + h0 + cc;
#pragma unroll
  for (int i = 0; i < 4; ++i) {
    float4 v = *(const float4*)(src + (size_t)(i * 16) * HDIM);
    *(float4*)&tile[rr + i * 16][cc] = v;
  }
  __syncthreads();
  int hr = tid >> 2;
  int dseg = (tid & 3) * 16;
  union { ushort_t s[16]; u16x8 v[2]; } o;
#pragma unroll
  for (int j = 0; j < 16; ++j) o.s[j] = f2b(tile[dseg + j][hr]);
  ushort_t* dst = fct + ((size_t)e * HDIM + h0 + hr) * DIM + d0 + dseg;
  *(u16x8*)dst = o.v[0];
  *(u16x8*)(dst + 8) = o.v[1];
}

// pj fp32 [E][D][HD] -> bf16 same layout (streaming)
__global__ __launch_bounds__(256) void cast_pj_kernel(
    const float* __restrict__ pj, ushort_t* __restrict__ pjb) {
  const size_t total = (size_t)NE * DIM * HDIM;
  size_t stride = (size_t)gridDim.x * 256 * 8;
  for (size_t i = ((size_t)blockIdx.x * 256 + threadIdx.x) * 8; i < total; i += stride) {
    f32x4 a = *(const f32x4*)(pj + i);
    f32x4 b = *(const f32x4*)(pj + i + 4);
    union { ushort_t s[8]; u16x8 v; } o;
    o.s[0] = f2b(a[0]); o.s[1] = f2b(a[1]); o.s[2] = f2b(a[2]); o.s[3] = f2b(a[3]);
    o.s[4] = f2b(b[0]); o.s[5] = f2b(b[1]); o.s[6] = f2b(b[2]); o.s[7] = f2b(b[3]);
    *(u16x8*)(pjb + i) = o.v;
  }
}

// ============================================================================
// 8-phase 256x256 GEMM body (m201 schedule): per phase {ds_reads | 1 half-tile
// stage | barrier | lgkm(0) | 16 MFMA (setprio) | barrier}; vmcnt(6) only at
// phases 4/8. Stage slots hazard-verified: ph1=A(T+1)h1, ph3=B(T+2)h0,
// ph4=B(T+2)h1+A(T+2)h0, ph5=A(T+2)h1, ph7=B(T+3)h0, ph8=B(T+3)h1+A(T+3)h0.
// ============================================================================
#define GEMM_MAIN_LOOP()                                                    \
  stB(0, 0, 0); stB(0, 0, 1); stA(0, 0, 0); stA(0, 0, 1);                   \
  stB(1, 1, 0); stB(1, 1, 1); stA(1, 1, 0);                                 \
  WAITV(6);                                                                 \
  BARRIER();                                                                \
  _Pragma("unroll 1")                                                       \
  for (int T = 0; T < NT; T += 2) {                                         \
    { const ushort_t* pA = As[0]; const ushort_t* pB = Bs[0];               \
      /* ph1 */                                                             \
      LOAD_AF(0); LOAD_BF(0);                                               \
      stA(1, T + 1, 1);                                                     \
      WAITL8(); SCHEDB();                                                   \
      BARRIER(); WAITL0(); SCHEDB();                                        \
      PH_MFMA(0, 0);                                                        \
      BARRIER();                                                            \
      /* ph2 */                                                             \
      LOAD_BF(1);                                                           \
      BARRIER(); WAITL0(); SCHEDB();                                        \
      PH_MFMA(0, 1);                                                        \
      BARRIER();                                                            \
      /* ph3 */                                                             \
      LOAD_AF(1);                                                           \
      if (T + 2 < NT) stB(0, T + 2, 0);                                     \
      BARRIER(); WAITL0(); SCHEDB();                                        \
      PH_MFMA(1, 0);                                                        \
      BARRIER();                                                            \
      /* ph4 */                                                             \
      if (T + 2 < NT) { stB(0, T + 2, 1); stA(0, T + 2, 0); WAITV(6); }     \
      else            { WAITV(0); }                                         \
      BARRIER(); SCHEDB();                                                  \
      PH_MFMA(1, 1);                                                        \
      BARRIER();                                                            \
    }                                                                       \
    { const ushort_t* pA = As[1]; const ushort_t* pB = Bs[1];               \
      /* ph5 */                                                             \
      LOAD_AF(0); LOAD_BF(0);                                               \
      if (T + 2 < NT) stA(0, T + 2, 1);                                     \
      WAITL8(); SCHEDB();                                                   \
      BARRIER(); WAITL0(); SCHEDB();                                        \
      PH_MFMA(0, 0);                                                        \
      BARRIER();                                                            \
      /* ph6 */                                                             \
      LOAD_BF(1);                                                           \
      BARRIER(); WAITL0(); SCHEDB();                                        \
      PH_MFMA(0, 1);                                                        \
      BARRIER();                                                            \
      /* ph7 */                                                             \
      LOAD_AF(1);                                                           \
      if (T + 3 < NT) stB(1, T + 3, 0);                                     \
      BARRIER(); WAITL0(); SCHEDB();                                        \
      PH_MFMA(1, 0);                                                        \
      BARRIER();                                                            \
      /* ph8 */                                                             \
      if (T + 3 < NT) { stB(1, T + 3, 1); stA(1, T + 3, 0); WAITV(6); }     \
      BARRIER(); SCHEDB();                                                  \
      PH_MFMA(1, 1);                                                        \
      BARRIER();                                                            \
    }                                                                       \
  }

// ---------------- GEMM1: H = relu(Xg @ fct^T)^2, bf16 out -------------------
__global__ __launch_bounds__(512, 2) void gemm1_kernel(
    const ushort_t* __restrict__ Xg, const ushort_t* __restrict__ fct,
    const int* __restrict__ offs, const int* __restrict__ tile_e,
    const int* __restrict__ tile_m, const int* __restrict__ ntiles,
    ushort_t* __restrict__ H) {
  __shared__ ushort_t As[2][16384];
  __shared__ ushort_t Bs[2][16384];

  // XCD swizzle: grid 16x24 = 384 = 48*8 (bijective)
  int lin = blockIdx.x + 16 * blockIdx.y;
  int sw = (lin & 7) * 48 + (lin >> 3);
  int bx = sw & 15, by = sw >> 4;
  if (by >= *ntiles) return;

  int e = tile_e[by];
  int mb = tile_m[by];
  int m0 = offs[e];
  int Me = offs[e + 1] - m0;
  int n0 = bx * 256;

  int tid = threadIdx.x;
  int wave = tid >> 6;
  int lane = tid & 63;
  int fr = lane & 15, kq = lane >> 4;
  int wr = wave & 1, wc = wave >> 1;

  // staging: thread covers 16B chunk; row = c*64 + tid>>3; pre-swizzled k src
  int swk = ((tid & 7) ^ ((tid >> 3) & 7)) * 8;
  const ushort_t* aSrc[4]; const ushort_t* bSrc[4];
#pragma unroll
  for (int c = 0; c < 4; ++c) {
    int r = c * 64 + (tid >> 3);
    int rg = mb + r; if (rg >= Me) rg = Me - 1;   // clamp tail rows
    aSrc[c] = Xg + (size_t)(m0 + rg) * DIM + swk;
    bSrc[c] = fct + ((size_t)e * HDIM + n0 + r) * DIM + swk;
  }
  int sdst = wave * 512;

  int aBase = (wr * 128 + fr) * 64;
  int bBase = (wc * 64 + fr) * 64;
  int ck[2] = { (kq ^ (fr & 7)) * 8, ((4 + kq) ^ (fr & 7)) * 8 };

  f32x4 acc[8][4] = {};
  bf16x8 af[4][2], bf[4][2];

  auto stA = [&](int p, int X, int h) __attribute__((always_inline)) {
    int ko = X * 64;
    gl2lds16(aSrc[2 * h] + ko,     &As[p][(2 * h) * 4096 + sdst]);
    gl2lds16(aSrc[2 * h + 1] + ko, &As[p][(2 * h + 1) * 4096 + sdst]);
  };
  auto stB = [&](int p, int X, int h) __attribute__((always_inline)) {
    int ko = X * 64;
    gl2lds16(bSrc[2 * h] + ko,     &Bs[p][(2 * h) * 4096 + sdst]);
    gl2lds16(bSrc[2 * h + 1] + ko, &Bs[p][(2 * h + 1) * 4096 + sdst]);
  };

  GEMM_MAIN_LOOP();

  int cq = kq * 4;
#pragma unroll
  for (int i = 0; i < 8; ++i) {
#pragma unroll
    for (int r = 0; r < 4; ++r) {
      int rl = wr * 128 + i * 16 + cq + r;
      int rg = mb + rl;
      if (rg < Me) {
        ushort_t* dst = H + (size_t)(m0 + rg) * HDIM + n0 + wc * 64 + fr;
#pragma unroll
        for (int j = 0; j < 4; ++j) {
          float v = acc[i][j][r];
          v = fmaxf(v, 0.f);
          dst[j * 16] = f2b(v * v);
        }
      }
    }
  }
}

// ---------------- GEMM2: out/P = H @ pjb^T (K-slice) ------------------------
// Identical 8-phase structure; B = pre-cast bf16 pjb (gl2lds, pre-swizzled).
// Epilogue dual path: P != nullptr -> fp32 partials + reduce pass;
// P == nullptr -> device-scope atomicAdd into zeroed out (scatter via sorted).
__global__ __launch_bounds__(512, 2) void gemm2_kernel(
    const ushort_t* __restrict__ Hm, const ushort_t* __restrict__ pjb,
    const int* __restrict__ offs, const int* __restrict__ tile_e,
    const int* __restrict__ tile_m, const int* __restrict__ ntiles,
    const int* __restrict__ sorted, float* P, float* __restrict__ out) {
  __shared__ ushort_t As[2][16384];
  __shared__ ushort_t Bs[2][16384];

  // XCD swizzle: grid 4x24x4 = 384
  int lin = blockIdx.x + 4 * (blockIdx.y + MAXT * blockIdx.z);
  int sw = (lin & 7) * 48 + (lin >> 3);
  int bx = sw & 3;
  int t2 = sw >> 2;
  int by = t2 % MAXT, bz = t2 / MAXT;
  if (by >= *ntiles) return;

  int e = tile_e[by];
  int mb = tile_m[by];
  int ks = bz;
  int m0 = offs[e];
  int Me = offs[e + 1] - m0;
  int n0 = bx * 256;
  int kbeg = ks * (HDIM / KSPLIT);

  int tid = threadIdx.x;
  int wave = tid >> 6;
  int lane = tid & 63;
  int fr = lane & 15, kq = lane >> 4;
  int wr = wave & 1, wc = wave >> 1;

  int swk = ((tid & 7) ^ ((tid >> 3) & 7)) * 8;
  const ushort_t* aSrc[4]; const ushort_t* bSrc[4];
#pragma unroll
  for (int c = 0; c < 4; ++c) {
    int r = c * 64 + (tid >> 3);
    int rg = mb + r; if (rg >= Me) rg = Me - 1;
    aSrc[c] = Hm + (size_t)(m0 + rg) * HDIM + kbeg + swk;
    bSrc[c] = pjb + ((size_t)e * DIM + n0 + r) * HDIM + kbeg + swk;
  }
  int sdst = wave * 512;

  int aBase = (wr * 128 + fr) * 64;
  int bBase = (wc * 64 + fr) * 64;
  int ck[2] = { (kq ^ (fr & 7)) * 8, ((4 + kq) ^ (fr & 7)) * 8 };

  f32x4 acc[8][4] = {};
  bf16x8 af[4][2], bf[4][2];

  auto stA = [&](int p, int X, int h) __attribute__((always_inline)) {
    int ko = X * 64;
    gl2lds16(aSrc[2 * h] + ko,     &As[p][(2 * h) * 4096 + sdst]);
    gl2lds16(aSrc[2 * h + 1] + ko, &As[p][(2 * h + 1) * 4096 + sdst]);
  };
  auto stB = [&](int p, int X, int h) __attribute__((always_inline)) {
    int ko = X * 64;
    gl2lds16(bSrc[2 * h] + ko,     &Bs[p][(2 * h) * 4096 + sdst]);
    gl2lds16(bSrc[2 * h + 1] + ko, &Bs[p][(2 * h + 1) * 4096 + sdst]);
  };

  GEMM_MAIN_LOOP();

  int cq = kq * 4;
  if (P) {
#pragma unroll
    for (int i = 0; i < 8; ++i) {
#pragma unroll
      for (int r = 0; r < 4; ++r) {
        int rl = wr * 128 + i * 16 + cq + r;
        int rg = mb + rl;
        if (rg < Me) {
          float* dst = P + ((size_t)ks * NTOK + (m0 + rg)) * DIM + n0 + wc * 64 + fr;
#pragma unroll
          for (int j = 0; j < 4; ++j) dst[j * 16] = acc[i][j][r];
        }
      }
    }
  } else {
#pragma unroll
    for (int i = 0; i < 8; ++i) {
#pragma unroll
      for (int r = 0; r < 4; ++r) {
        int rl = wr * 128 + i * 16 + cq + r;
        int rg = mb + rl;
        if (rg < Me) {
          int tok = sorted[m0 + rg];
          float* dst = out + (size_t)tok * DIM + n0 + wc * 64 + fr;
#pragma unroll
          for (int j = 0; j < 4; ++j) atomicAdd(&dst[j * 16], acc[i][j][r]);
        }
      }
    }
  }
}

// ---------------- reduce: out[tok] = sum_ks P[ks][pos], coalesced -----------
__global__ __launch_bounds__(256) void reduce_kernel(
    const float* __restrict__ P, const int* __restrict__ sorted,
    float* __restrict__ out) {
  int pos = blockIdx.x;
  int tok = sorted[pos];
  int i = threadIdx.x;
  size_t base = (size_t)pos * DIM + i * 4;
  const size_t S = (size_t)NTOK * DIM;
  f32x4 s = *(const f32x4*)(P + base) + *(const f32x4*)(P + S + base) +
            *(const f32x4*)(P + 2 * S + base) + *(const f32x4*)(P + 3 * S + base);
  *(f32x4*)(out + (size_t)tok * DIM + i * 4) = s;
}

// ---------------- launch -----------------------------------------------------
extern "C" void kernel_launch(void* const* d_in, const int* in_sizes, int n_in,
                              void* d_out, int out_size, void* d_ws, size_t ws_size,
                              hipStream_t stream) {
  const float* x  = (const float*)d_in[0];
  const float* rw = (const float*)d_in[1];
  const float* fc = (const float*)d_in[2];
  const float* pj = (const float*)d_in[3];
  float* out = (float*)d_out;
  char* ws = (char*)d_ws;

  int* eid        = (int*)(ws + 0x0000);
  int* rank       = (int*)(ws + 0x4000);
  int* cnt        = (int*)(ws + 0x8000);
  int* offs       = (int*)(ws + 0x8100);
  int* tile_e     = (int*)(ws + 0x8200);
  int* tile_m     = (int*)(ws + 0x8600);
  int* ntiles     = (int*)(ws + 0x8a00);
  int* sorted     = (int*)(ws + 0x9000);
  ushort_t* Xg    = (ushort_t*)(ws + 0x10000);    // 8MB  [4096][1024] bf16
  ushort_t* H     = (ushort_t*)(ws + 0x810000);   // 32MB [4096][4096] bf16
  ushort_t* W     = (ushort_t*)(ws + 0x2810000);  // 64MB: fct (gemm1), then pjb (gemm2)

  // P partials (64MB) live past the 104MB mark only if the workspace allows;
  // otherwise gemm2 accumulates atomically into zeroed out.
  const size_t pOff = 0x6810000ULL;
  const size_t pBytes = (size_t)KSPLIT * NTOK * DIM * sizeof(float);
  bool bigws = ws_size >= pOff + pBytes;
  float* P = bigws ? (float*)(ws + pOff) : nullptr;

  hipMemsetAsync(cnt, 0, 32, stream);
  if (!bigws) hipMemsetAsync(out, 0, (size_t)NTOK * DIM * sizeof(float), stream);
  router_kernel<<<NTOK / 32, 256, 0, stream>>>(x, rw, eid, rank, cnt);
  scan_kernel<<<1, 64, 0, stream>>>(cnt, offs, tile_e, tile_m, ntiles);
  gather_kernel<<<NTOK, 256, 0, stream>>>(x, eid, rank, offs, sorted, Xg);
  transpose_fc_kernel<<<dim3(HDIM / 64, DIM / 64, NE), 256, 0, stream>>>(fc, W);
  gemm1_kernel<<<dim3(HDIM / 256, MAXT), 512, 0, stream>>>(Xg, W, offs, tile_e, tile_m, ntiles, H);
  cast_pj_kernel<<<4096, 256, 0, stream>>>(pj, W);  // overwrites fct (dead)
  gemm2_kernel<<<dim3(DIM / 256, MAXT, KSPLIT), 512, 0, stream>>>(
      H, W, offs, tile_e, tile_m, ntiles, sorted, P, out);
  if (bigws) reduce_kernel<<<NTOK, 256, 0, stream>>>(P, sorted, out);
}